// Round 1
// baseline (60.986 us; speedup 1.0000x reference)
//
#include <hip/hip_runtime.h>
#include <math.h>

#define HW 256
#define NPTS (HW * HW)
#define NP4 (NPTS / 4)
#define NKPT 68
#define NBATCH 128

// ---------------------------------------------------------------------------
// Kernel 1: per-batch similarity transform estimation (one block per batch).
// Threads 0..67 gather keypoints; thread 0 does the 3x3 work serially in
// double (trivial cost). R = V U^T from SVD(H) == orthogonal polar factor of
// H^T (no det correction in the reference), computed via Newton iteration
//   X <- 0.5 * (X + X^-T),  X^-T = cof(X)/det(X)  for 3x3.
// Output per batch: 12 floats = [ (s*R)[0..8] row-major , t[0..2] ].
// ---------------------------------------------------------------------------
__global__ __launch_bounds__(128) void kpt_tform_kernel(
    const float* __restrict__ Offset,   // (B,3,HW,HW)
    const float* __restrict__ Posmap,   // (B,3,HW,HW)
    const float* __restrict__ meanp,    // (3,HW,HW)
    const int*   __restrict__ uv,       // (68,2)
    float* __restrict__ Rt)             // (B,12)
{
    const int b = blockIdx.x;
    __shared__ double src[NKPT][3];
    __shared__ double dst[NKPT][3];

    const int i = threadIdx.x;
    if (i < NKPT) {
        const int u = uv[2 * i + 0];
        const int v = uv[2 * i + 1];
        const int pix = u * HW + v;
        const float* ob = Offset + (size_t)b * 3 * NPTS;
        const float* pb = Posmap + (size_t)b * 3 * NPTS;
#pragma unroll
        for (int c = 0; c < 3; ++c) {
            src[i][c] = (double)ob[c * NPTS + pix] * 6.0 + (double)meanp[c * NPTS + pix];
            dst[i][c] = (double)pb[c * NPTS + pix];
        }
    }
    __syncthreads();
    if (i != 0) return;

    // --- scale s = sum||dst_k - dst_0|| / sum||src_k - src_0||
    double d1 = 0.0, d2 = 0.0;
    for (int k = 1; k < NKPT; ++k) {
        double dx = src[k][0] - src[0][0];
        double dy = src[k][1] - src[0][1];
        double dz = src[k][2] - src[0][2];
        d1 += sqrt(dx * dx + dy * dy + dz * dz);
        dx = dst[k][0] - dst[0][0];
        dy = dst[k][1] - dst[0][1];
        dz = dst[k][2] - dst[0][2];
        d2 += sqrt(dx * dx + dy * dy + dz * dz);
    }
    const double s = d2 / d1;

    // --- means of A = s*src and B = dst
    double mA[3] = {0, 0, 0}, mB[3] = {0, 0, 0};
    for (int k = 0; k < NKPT; ++k) {
#pragma unroll
        for (int c = 0; c < 3; ++c) {
            mA[c] += s * src[k][c];
            mB[c] += dst[k][c];
        }
    }
#pragma unroll
    for (int c = 0; c < 3; ++c) { mA[c] *= (1.0 / NKPT); mB[c] *= (1.0 / NKPT); }

    // --- H = AA^T BB ; H[r][c] = sum_k (A_k - mA)[r] * (B_k - mB)[c]
    double Hm[3][3] = {{0,0,0},{0,0,0},{0,0,0}};
    for (int k = 0; k < NKPT; ++k) {
        double a[3], bb[3];
#pragma unroll
        for (int c = 0; c < 3; ++c) {
            a[c]  = s * src[k][c] - mA[c];
            bb[c] = dst[k][c] - mB[c];
        }
#pragma unroll
        for (int r = 0; r < 3; ++r)
#pragma unroll
            for (int c = 0; c < 3; ++c)
                Hm[r][c] += a[r] * bb[c];
    }

    // --- R = orthogonal polar factor of X0 = H^T (== V U^T)
    double X[3][3];
#pragma unroll
    for (int r = 0; r < 3; ++r)
#pragma unroll
        for (int c = 0; c < 3; ++c)
            X[r][c] = Hm[c][r];

    double nf = 0.0;
#pragma unroll
    for (int r = 0; r < 3; ++r)
#pragma unroll
        for (int c = 0; c < 3; ++c)
            nf += X[r][c] * X[r][c];
    nf = 1.0 / sqrt(nf);
#pragma unroll
    for (int r = 0; r < 3; ++r)
#pragma unroll
        for (int c = 0; c < 3; ++c)
            X[r][c] *= nf;

    for (int it = 0; it < 30; ++it) {
        double C[3][3];
        // cofactor rows: row0 = r1 x r2, row1 = r2 x r0, row2 = r0 x r1
        C[0][0] = X[1][1] * X[2][2] - X[1][2] * X[2][1];
        C[0][1] = X[1][2] * X[2][0] - X[1][0] * X[2][2];
        C[0][2] = X[1][0] * X[2][1] - X[1][1] * X[2][0];
        C[1][0] = X[2][1] * X[0][2] - X[2][2] * X[0][1];
        C[1][1] = X[2][2] * X[0][0] - X[2][0] * X[0][2];
        C[1][2] = X[2][0] * X[0][1] - X[2][1] * X[0][0];
        C[2][0] = X[0][1] * X[1][2] - X[0][2] * X[1][1];
        C[2][1] = X[0][2] * X[1][0] - X[0][0] * X[1][2];
        C[2][2] = X[0][0] * X[1][1] - X[0][1] * X[1][0];
        const double det = X[0][0] * C[0][0] + X[0][1] * C[0][1] + X[0][2] * C[0][2];
        const double inv = 0.5 / det;
#pragma unroll
        for (int r = 0; r < 3; ++r)
#pragma unroll
            for (int c = 0; c < 3; ++c)
                X[r][c] = 0.5 * X[r][c] + C[r][c] * inv;
    }

    // t = mB - R * mA   (mA already includes the s factor)
    float* o = Rt + b * 12;
#pragma unroll
    for (int r = 0; r < 3; ++r) {
#pragma unroll
        for (int c = 0; c < 3; ++c)
            o[r * 3 + c] = (float)(s * X[r][c]);
        o[9 + r] = (float)(mB[r] - (X[r][0] * mA[0] + X[r][1] * mA[1] + X[r][2] * mA[2]));
    }
}

// ---------------------------------------------------------------------------
// Kernel 2: out[b,r,i] = sum_c (s*R)[r][c] * (Offset[b,c,i]*6 + mean[c,i]) + t[r]
// float4-vectorized streaming pass. One block handles 256*4 pixels of one batch.
// ---------------------------------------------------------------------------
__global__ __launch_bounds__(256) void apply_tform_kernel(
    const float4* __restrict__ Off,     // (B,3,NP4) as float4
    const float4* __restrict__ meanp,   // (3,NP4) as float4
    const float*  __restrict__ Rt,      // (B,12)
    float4* __restrict__ out)           // (B,3,NP4) as float4
{
    const int b = blockIdx.y;
    const int g = blockIdx.x * blockDim.x + threadIdx.x;   // pixel-group index

    __shared__ float srt[12];
    if (threadIdx.x < 12) srt[threadIdx.x] = Rt[b * 12 + threadIdx.x];
    __syncthreads();

    const float R00 = srt[0], R01 = srt[1], R02 = srt[2];
    const float R10 = srt[3], R11 = srt[4], R12 = srt[5];
    const float R20 = srt[6], R21 = srt[7], R22 = srt[8];
    const float t0 = srt[9], t1 = srt[10], t2 = srt[11];

    const size_t base = (size_t)b * 3 * NP4;
    const float4 ox = Off[base + 0 * NP4 + g];
    const float4 oy = Off[base + 1 * NP4 + g];
    const float4 oz = Off[base + 2 * NP4 + g];
    const float4 mx = meanp[0 * NP4 + g];
    const float4 my = meanp[1 * NP4 + g];
    const float4 mz = meanp[2 * NP4 + g];

    float4 r0, r1, r2;
#define DO_COMP(comp)                                                        \
    {                                                                        \
        const float px = fmaf(ox.comp, 6.0f, mx.comp);                       \
        const float py = fmaf(oy.comp, 6.0f, my.comp);                       \
        const float pz = fmaf(oz.comp, 6.0f, mz.comp);                       \
        r0.comp = fmaf(R00, px, fmaf(R01, py, fmaf(R02, pz, t0)));           \
        r1.comp = fmaf(R10, px, fmaf(R11, py, fmaf(R12, pz, t1)));           \
        r2.comp = fmaf(R20, px, fmaf(R21, py, fmaf(R22, pz, t2)));           \
    }
    DO_COMP(x)
    DO_COMP(y)
    DO_COMP(z)
    DO_COMP(w)
#undef DO_COMP

    out[base + 0 * NP4 + g] = r0;
    out[base + 1 * NP4 + g] = r1;
    out[base + 2 * NP4 + g] = r2;
}

extern "C" void kernel_launch(void* const* d_in, const int* in_sizes, int n_in,
                              void* d_out, int out_size, void* d_ws, size_t ws_size,
                              hipStream_t stream) {
    const float* Offset = (const float*)d_in[0];   // (128,3,256,256)
    const float* Posmap = (const float*)d_in[1];   // (128,3,256,256)
    const float* meanp  = (const float*)d_in[2];   // (3,256,256)
    const int*   uv     = (const int*)d_in[3];     // (68,2)
    float* out = (float*)d_out;
    float* Rt  = (float*)d_ws;                     // 128*12 floats

    kpt_tform_kernel<<<NBATCH, 128, 0, stream>>>(Offset, Posmap, meanp, uv, Rt);

    dim3 grid(NP4 / 256, NBATCH);
    apply_tform_kernel<<<grid, 256, 0, stream>>>(
        (const float4*)Offset, (const float4*)meanp, Rt, (float4*)out);
}

// Round 2
// 43.799 us; speedup vs baseline: 1.3924x; 1.3924x over previous
//
#include <hip/hip_runtime.h>
#include <math.h>

#define HW 256
#define NPTS (HW * HW)
#define NP4 (NPTS / 4)
#define NKPT 68
#define NBATCH 128

typedef float f32x4 __attribute__((ext_vector_type(4)));

// ---------------------------------------------------------------------------
// Kernel 1: per-batch similarity transform (one block of 128 threads per batch).
// Threads 0..67 gather keypoints and compute per-point terms; 17 scalars are
// wave-reduced (shfl) + combined across the 2 waves in LDS. Thread 0 then does
// the 3x3 polar decomposition in fp32 via Newton iteration
//   X <- 0.5*(X + X^-T),  X^-T = cof(X)/det(X).
// R = V U^T from SVD(H) == polar factor of H^T; invariant to positive scale,
// so H is built WITHOUT the s factor: H = sum(src*dst^T) - N*mSrc*mDst^T.
// Output per batch: 12 floats = [ (s*R)[0..8] row-major , t[0..2] ].
// ---------------------------------------------------------------------------
__global__ __launch_bounds__(128) void kpt_tform_kernel(
    const float* __restrict__ Offset,   // (B,3,HW,HW)
    const float* __restrict__ Posmap,   // (B,3,HW,HW)
    const float* __restrict__ meanp,    // (3,HW,HW)
    const int*   __restrict__ uv,       // (68,2)
    float* __restrict__ Rt)             // (B,12)
{
    const int b    = blockIdx.x;
    const int i    = threadIdx.x;
    const int wave = i >> 6;
    const int lane = i & 63;

    __shared__ float s0[6];            // src0[3], dst0[3]
    __shared__ float partial[2][17];

    float src[3] = {0.f, 0.f, 0.f};
    float dst[3] = {0.f, 0.f, 0.f};

    if (i < NKPT) {
        const int u = uv[2 * i + 0];
        const int v = uv[2 * i + 1];
        const int pix = u * HW + v;
        const float* ob = Offset + (size_t)b * 3 * NPTS;
        const float* pb = Posmap + (size_t)b * 3 * NPTS;
#pragma unroll
        for (int c = 0; c < 3; ++c) {
            src[c] = fmaf(ob[c * NPTS + pix], 6.0f, meanp[c * NPTS + pix]);
            dst[c] = pb[c * NPTS + pix];
        }
    }
    if (i == 0) {
#pragma unroll
        for (int c = 0; c < 3; ++c) { s0[c] = src[c]; s0[3 + c] = dst[c]; }
    }
    __syncthreads();

    // per-thread terms
    float vals[17];
    float d1 = 0.f, d2 = 0.f;
    if (i >= 1 && i < NKPT) {
        float dx = src[0] - s0[0], dy = src[1] - s0[1], dz = src[2] - s0[2];
        d1 = sqrtf(dx * dx + dy * dy + dz * dz);
        dx = dst[0] - s0[3]; dy = dst[1] - s0[4]; dz = dst[2] - s0[5];
        d2 = sqrtf(dx * dx + dy * dy + dz * dz);
    }
    vals[0] = d1;
    vals[1] = d2;
#pragma unroll
    for (int c = 0; c < 3; ++c) { vals[2 + c] = src[c]; vals[5 + c] = dst[c]; }
#pragma unroll
    for (int r = 0; r < 3; ++r)
#pragma unroll
        for (int c = 0; c < 3; ++c)
            vals[8 + r * 3 + c] = src[r] * dst[c];

    // wave reduction (64 lanes), then cross-wave combine via LDS
#pragma unroll
    for (int j = 0; j < 17; ++j) {
        float v = vals[j];
#pragma unroll
        for (int off = 32; off > 0; off >>= 1)
            v += __shfl_down(v, off);
        if (lane == 0) partial[wave][j] = v;
    }
    __syncthreads();
    if (i != 0) return;

    float sum[17];
#pragma unroll
    for (int j = 0; j < 17; ++j) sum[j] = partial[0][j] + partial[1][j];

    const float s = sum[1] / sum[0];
    const float invN = 1.0f / (float)NKPT;
    float mS[3], mD[3];
#pragma unroll
    for (int c = 0; c < 3; ++c) { mS[c] = sum[2 + c] * invN; mD[c] = sum[5 + c] * invN; }

    float Hm[3][3];
#pragma unroll
    for (int r = 0; r < 3; ++r)
#pragma unroll
        for (int c = 0; c < 3; ++c)
            Hm[r][c] = sum[8 + r * 3 + c] - (float)NKPT * mS[r] * mD[c];

    // X0 = H^T / ||H||_F ; Newton polar iteration in fp32
    float X[3][3];
#pragma unroll
    for (int r = 0; r < 3; ++r)
#pragma unroll
        for (int c = 0; c < 3; ++c)
            X[r][c] = Hm[c][r];

    float nf = 0.f;
#pragma unroll
    for (int r = 0; r < 3; ++r)
#pragma unroll
        for (int c = 0; c < 3; ++c)
            nf += X[r][c] * X[r][c];
    nf = rsqrtf(nf);
#pragma unroll
    for (int r = 0; r < 3; ++r)
#pragma unroll
        for (int c = 0; c < 3; ++c)
            X[r][c] *= nf;

    for (int it = 0; it < 20; ++it) {
        float C[3][3];
        C[0][0] = X[1][1] * X[2][2] - X[1][2] * X[2][1];
        C[0][1] = X[1][2] * X[2][0] - X[1][0] * X[2][2];
        C[0][2] = X[1][0] * X[2][1] - X[1][1] * X[2][0];
        C[1][0] = X[2][1] * X[0][2] - X[2][2] * X[0][1];
        C[1][1] = X[2][2] * X[0][0] - X[2][0] * X[0][2];
        C[1][2] = X[2][0] * X[0][1] - X[2][1] * X[0][0];
        C[2][0] = X[0][1] * X[1][2] - X[0][2] * X[1][1];
        C[2][1] = X[0][2] * X[1][0] - X[0][0] * X[1][2];
        C[2][2] = X[0][0] * X[1][1] - X[0][1] * X[1][0];
        const float det = X[0][0] * C[0][0] + X[0][1] * C[0][1] + X[0][2] * C[0][2];
        const float inv = 0.5f / det;
#pragma unroll
        for (int r = 0; r < 3; ++r)
#pragma unroll
            for (int c = 0; c < 3; ++c)
                X[r][c] = 0.5f * X[r][c] + C[r][c] * inv;
    }

    // outputs: s*R and t = mD - s*(R*mS)
    float* o = Rt + b * 12;
#pragma unroll
    for (int r = 0; r < 3; ++r) {
#pragma unroll
        for (int c = 0; c < 3; ++c)
            o[r * 3 + c] = s * X[r][c];
        o[9 + r] = mD[r] - s * (X[r][0] * mS[0] + X[r][1] * mS[1] + X[r][2] * mS[2]);
    }
}

// ---------------------------------------------------------------------------
// Kernel 2: out[b,r,i] = sum_c (s*R)[r][c] * (Offset[b,c,i]*6 + mean[c,i]) + t[r]
// float4-vectorized streaming pass; nontemporal stores (output never re-read).
// ---------------------------------------------------------------------------
__global__ __launch_bounds__(256) void apply_tform_kernel(
    const f32x4* __restrict__ Off,      // (B,3,NP4)
    const f32x4* __restrict__ meanp,    // (3,NP4)
    const float* __restrict__ Rt,       // (B,12)
    f32x4* __restrict__ out)            // (B,3,NP4)
{
    const int b = blockIdx.y;
    const int g = blockIdx.x * blockDim.x + threadIdx.x;   // pixel-group index

    __shared__ float srt[12];
    if (threadIdx.x < 12) srt[threadIdx.x] = Rt[b * 12 + threadIdx.x];
    __syncthreads();

    const float R00 = srt[0], R01 = srt[1], R02 = srt[2];
    const float R10 = srt[3], R11 = srt[4], R12 = srt[5];
    const float R20 = srt[6], R21 = srt[7], R22 = srt[8];
    const float t0 = srt[9], t1 = srt[10], t2 = srt[11];

    const size_t base = (size_t)b * 3 * NP4;
    const f32x4 ox = Off[base + 0 * NP4 + g];
    const f32x4 oy = Off[base + 1 * NP4 + g];
    const f32x4 oz = Off[base + 2 * NP4 + g];
    const f32x4 mx = meanp[0 * NP4 + g];
    const f32x4 my = meanp[1 * NP4 + g];
    const f32x4 mz = meanp[2 * NP4 + g];

    f32x4 r0, r1, r2;
#pragma unroll
    for (int j = 0; j < 4; ++j) {
        const float px = fmaf(ox[j], 6.0f, mx[j]);
        const float py = fmaf(oy[j], 6.0f, my[j]);
        const float pz = fmaf(oz[j], 6.0f, mz[j]);
        r0[j] = fmaf(R00, px, fmaf(R01, py, fmaf(R02, pz, t0)));
        r1[j] = fmaf(R10, px, fmaf(R11, py, fmaf(R12, pz, t1)));
        r2[j] = fmaf(R20, px, fmaf(R21, py, fmaf(R22, pz, t2)));
    }

    __builtin_nontemporal_store(r0, &out[base + 0 * NP4 + g]);
    __builtin_nontemporal_store(r1, &out[base + 1 * NP4 + g]);
    __builtin_nontemporal_store(r2, &out[base + 2 * NP4 + g]);
}

extern "C" void kernel_launch(void* const* d_in, const int* in_sizes, int n_in,
                              void* d_out, int out_size, void* d_ws, size_t ws_size,
                              hipStream_t stream) {
    const float* Offset = (const float*)d_in[0];   // (128,3,256,256)
    const float* Posmap = (const float*)d_in[1];   // (128,3,256,256)
    const float* meanp  = (const float*)d_in[2];   // (3,256,256)
    const int*   uv     = (const int*)d_in[3];     // (68,2)
    float* out = (float*)d_out;
    float* Rt  = (float*)d_ws;                     // 128*12 floats

    kpt_tform_kernel<<<NBATCH, 128, 0, stream>>>(Offset, Posmap, meanp, uv, Rt);

    dim3 grid(NP4 / 256, NBATCH);
    apply_tform_kernel<<<grid, 256, 0, stream>>>(
        (const f32x4*)Offset, (const f32x4*)meanp, Rt, (f32x4*)out);
}